// Round 5
// baseline (333.861 us; speedup 1.0000x reference)
//
#include <hip/hip_runtime.h>
#include <stdint.h>

#define TEMPERATURE 0.07f
#define MARGIN 0.1f
#define D_DIM 512          // elements per row
#define BM 128
#define BN 256
#define QSCALE 32.0f       // pre-quantization scale (2^5)
#define SCALE_BYTE 0x7A7A7A7A  // e8m0 2^-5 replicated (compensates QSCALE^2)
#define LOG2E 1.4426950408889634f
#define LN2 0.6931471805599453f

// Packed fragment-major layout (per matrix, N*512 bytes):
//   elem [row][k] -> (row>>4)*8192 + (k>>7)*2048 + ((k>>5)&3)*512
//                    + (row&15)*32 + (k&31)
// MFMA fragment (panel p, kstep ks) for lane L = 32 contiguous bytes at
//   p*8192 + ks*2048 + L*32

typedef int v8i32 __attribute__((ext_vector_type(8)));
typedef float f32x4 __attribute__((ext_vector_type(4)));

__device__ __forceinline__ float softplus(float x) {
    return fmaxf(x, 0.0f) + __logf(1.0f + __expf(-fabsf(x)));
}

// Fused: L2-normalize row of S and T, quantize to e4m3 (x32), write packed
// fragment-major layout, emit diagonal correction. One wave per row.
__global__ __launch_bounds__(256) void norm_quant_pack_kernel(
    const float* __restrict__ s_in, const float* __restrict__ t_in,
    unsigned char* __restrict__ sp, unsigned char* __restrict__ tp,
    float* __restrict__ corr) {
    const int row = blockIdx.x * 4 + (threadIdx.x >> 6);
    const int lane = threadIdx.x & 63;
    const float4* s4 = (const float4*)(s_in + (size_t)row * D_DIM);
    const float4* t4 = (const float4*)(t_in + (size_t)row * D_DIM);
    float4 a0 = s4[lane * 2], a1 = s4[lane * 2 + 1];
    float4 b0 = t4[lane * 2], b1 = t4[lane * 2 + 1];
    float ss = a0.x * a0.x + a0.y * a0.y + a0.z * a0.z + a0.w * a0.w +
               a1.x * a1.x + a1.y * a1.y + a1.z * a1.z + a1.w * a1.w;
    float tt = b0.x * b0.x + b0.y * b0.y + b0.z * b0.z + b0.w * b0.w +
               b1.x * b1.x + b1.y * b1.y + b1.z * b1.z + b1.w * b1.w;
    float st = a0.x * b0.x + a0.y * b0.y + a0.z * b0.z + a0.w * b0.w +
               a1.x * b1.x + a1.y * b1.y + a1.z * b1.z + a1.w * b1.w;
#pragma unroll
    for (int off = 32; off > 0; off >>= 1) {
        ss += __shfl_down(ss, off);
        tt += __shfl_down(tt, off);
        st += __shfl_down(st, off);
    }
    ss = __shfl(ss, 0);
    tt = __shfl(tt, 0);
    const float ns = fmaxf(sqrtf(ss), 1e-12f);
    const float nt = fmaxf(sqrtf(tt), 1e-12f);
    if (lane == 0) {
        const float l = st / (ns * nt) * (1.0f / TEMPERATURE);
        corr[row] = softplus(-l - MARGIN) - softplus(l - MARGIN);
    }
    const float is = QSCALE / ns, it = QSCALE / nt;
    int s_lo = 0, s_hi = 0, t_lo = 0, t_hi = 0;
    s_lo = __builtin_amdgcn_cvt_pk_fp8_f32(a0.x * is, a0.y * is, s_lo, false);
    s_lo = __builtin_amdgcn_cvt_pk_fp8_f32(a0.z * is, a0.w * is, s_lo, true);
    s_hi = __builtin_amdgcn_cvt_pk_fp8_f32(a1.x * is, a1.y * is, s_hi, false);
    s_hi = __builtin_amdgcn_cvt_pk_fp8_f32(a1.z * is, a1.w * is, s_hi, true);
    t_lo = __builtin_amdgcn_cvt_pk_fp8_f32(b0.x * it, b0.y * it, t_lo, false);
    t_lo = __builtin_amdgcn_cvt_pk_fp8_f32(b0.z * it, b0.w * it, t_lo, true);
    t_hi = __builtin_amdgcn_cvt_pk_fp8_f32(b1.x * it, b1.y * it, t_hi, false);
    t_hi = __builtin_amdgcn_cvt_pk_fp8_f32(b1.z * it, b1.w * it, t_hi, true);
    const size_t off = (size_t)(row >> 4) * 8192 + (lane >> 4) * 2048 +
                       ((lane >> 2) & 3) * 512 + (row & 15) * 32 + (lane & 3) * 8;
    *(uint2*)(sp + off) = make_uint2((unsigned)s_lo, (unsigned)s_hi);
    *(uint2*)(tp + off) = make_uint2((unsigned)t_lo, (unsigned)t_hi);
}

// 128x256 logits tile; 4 waves 2x2, wave tile 64x128 = 4x8 of
// mfma_scale_f32_16x16x128_f8f6f4. No LDS/barriers in K-loop; explicit
// fragment double-buffer (load ks+1 while MFMAing ks). Log-batched epilogue.
__global__ __launch_bounds__(256) void gemm_loss_kernel(
    const unsigned char* __restrict__ Sp, const unsigned char* __restrict__ Tp,
    float* __restrict__ partial) {
    __shared__ float wsums[4];

    const int tid = threadIdx.x;
    const int wave = tid >> 6;
    const int lane = tid & 63;
    const int wm = wave >> 1;
    const int wn = wave & 1;

    // XCD super-tile swizzle.
    const int b = blockIdx.x;
    const int xcd = b & 7;
    const int slot = b >> 3;
    const int sidx = slot >> 6;
    const int within = slot & 63;
    const int st_ = sidx * 8 + xcd;
    const int tm = (st_ >> 4) * 16 + (within >> 2);   // 0..127
    const int tn_ = (st_ & 15) * 4 + (within & 3);    // 0..63

    const unsigned char* Abase =
        Sp + (size_t)(tm * 8 + wm * 4) * 8192 + lane * 32;
    const unsigned char* Bbase =
        Tp + (size_t)(tn_ * 16 + wn * 8) * 8192 + lane * 32;

    f32x4 acc[4][8];
#pragma unroll
    for (int i = 0; i < 4; ++i)
#pragma unroll
        for (int j = 0; j < 8; ++j) acc[i][j] = (f32x4){0.f, 0.f, 0.f, 0.f};

    v8i32 aF[2][4], bF[2][8];
#define LOADF(buf, ks)                                                         \
    do {                                                                       \
        _Pragma("unroll") for (int mt = 0; mt < 4; ++mt) aF[buf][mt] =         \
            *(const v8i32*)(Abase + (size_t)mt * 8192 + (ks) * 2048);          \
        _Pragma("unroll") for (int nt = 0; nt < 8; ++nt) bF[buf][nt] =         \
            *(const v8i32*)(Bbase + (size_t)nt * 8192 + (ks) * 2048);          \
    } while (0)

    LOADF(0, 0);
#pragma unroll
    for (int ks = 0; ks < 4; ++ks) {
        const int cur = ks & 1;
        if (ks < 3) LOADF(cur ^ 1, ks + 1);
#pragma unroll
        for (int nt = 0; nt < 8; ++nt)
#pragma unroll
            for (int mt = 0; mt < 4; ++mt)
                acc[mt][nt] = __builtin_amdgcn_mfma_scale_f32_16x16x128_f8f6f4(
                    aF[cur][mt], bF[cur][nt], acc[mt][nt], 0 /*cbsz*/,
                    0 /*blgp*/, 0, SCALE_BYTE, 0, SCALE_BYTE);
    }
#undef LOADF

    // Log-batched epilogue in log2-space:
    // y = acc*(log2e/T) - margin*log2e;  sum softplus = ln2*(sum max(y,0)
    //   + sum_groups log2(prod_8 (1+2^-|y|))).  Diagonal fixed by corr.
    const float C1 = LOG2E / TEMPERATURE;
    const float C2 = -MARGIN * LOG2E;
    float lin = 0.0f, lgs = 0.0f;
#pragma unroll
    for (int mt = 0; mt < 4; ++mt)
#pragma unroll
        for (int nt = 0; nt < 8; nt += 2) {
            float prod = 1.0f;
#pragma unroll
            for (int h = 0; h < 2; ++h)
#pragma unroll
                for (int r = 0; r < 4; ++r) {
                    const float y = fmaf(acc[mt][nt + h][r], C1, C2);
                    lin += fmaxf(y, 0.0f);
                    prod *= 1.0f + exp2f(-fabsf(y));
                }
            lgs += log2f(prod);
        }
    float lsum = LN2 * (lin + lgs);
#pragma unroll
    for (int off = 32; off > 0; off >>= 1) lsum += __shfl_down(lsum, off);
    if (lane == 0) wsums[wave] = lsum;
    __syncthreads();
    if (tid == 0)
        partial[b] = wsums[0] + wsums[1] + wsums[2] + wsums[3];
}

__global__ __launch_bounds__(256) void reduce_kernel(
    const float* __restrict__ partial, int nPartials,
    const float* __restrict__ corr, int nCorr, int N,
    float* __restrict__ out) {
    float s = 0.0f;
    const float4* p4 = (const float4*)partial;
    const float4* c4 = (const float4*)corr;
    for (int i = threadIdx.x; i < nPartials / 4; i += 256) {
        float4 v = p4[i];
        s += v.x + v.y + v.z + v.w;
    }
    for (int i = threadIdx.x; i < nCorr / 4; i += 256) {
        float4 v = c4[i];
        s += v.x + v.y + v.z + v.w;
    }
#pragma unroll
    for (int off = 32; off > 0; off >>= 1) s += __shfl_down(s, off);
    __shared__ float ws[4];
    const int wave = threadIdx.x >> 6;
    const int lane = threadIdx.x & 63;
    if (lane == 0) ws[wave] = s;
    __syncthreads();
    if (threadIdx.x == 0) out[0] = (ws[0] + ws[1] + ws[2] + ws[3]) / (float)N;
}

extern "C" void kernel_launch(void* const* d_in, const int* in_sizes, int n_in,
                              void* d_out, int out_size, void* d_ws, size_t ws_size,
                              hipStream_t stream) {
    (void)n_in; (void)out_size; (void)ws_size;
    const float* s_in = (const float*)d_in[0];
    const float* t_in = (const float*)d_in[1];
    const int N = in_sizes[0] / D_DIM;  // 16384

    unsigned char* sp = (unsigned char*)d_ws;                    // N*512 fp8 packed
    unsigned char* tp = sp + (size_t)N * D_DIM;                  // N*512 fp8 packed
    float* partial = (float*)(tp + (size_t)N * D_DIM);           // 8192 floats
    const int nPartials = (N / BM) * (N / BN);
    float* corr = partial + nPartials;                           // N floats

    norm_quant_pack_kernel<<<N / 4, 256, 0, stream>>>(s_in, t_in, sp, tp, corr);
    gemm_loss_kernel<<<nPartials, 256, 0, stream>>>(sp, tp, partial);
    reduce_kernel<<<1, 256, 0, stream>>>(partial, nPartials, corr, N, N,
                                         (float*)d_out);
}